// Round 11
// baseline (117.572 us; speedup 1.0000x reference)
//
#include <hip/hip_runtime.h>

#define H 1024
#define W 1024
#define NB 8
#define NT 256

#define SROW 24      /* staged input rows  (16 out + 8 halo) */
#define SCOL 80      /* staged input cols  (64 out + 8 halo + 8 tile slack) */
#define SPITCH 81    /* stage pitch: +1 pad -> column reads spread banks */
#define TPITCH 36    /* transpose pitch (f32): 144B rows, 16B-aligned, <=2-way banks */

typedef __attribute__((ext_vector_type(8))) short bf16x8;  /* 8 bf16 = 4 VGPR */
typedef __attribute__((ext_vector_type(4))) float f32x4;

typedef union { bf16x8 v; unsigned u[4]; } bfr;

__global__ void ncc_zero(double* acc) { *acc = 0.0; }

__global__ void ncc_finalize(const double* __restrict__ acc, float* __restrict__ out) {
    out[0] = 1.0f - (float)(*acc * (1.0 / 8388608.0));  // 8*1024*1024 pixels
}

// pack 2 f32 -> u32 of 2 bf16 (lo = s0, hi = s1), RNE
__device__ __forceinline__ unsigned cvt2(float lo, float hi) {
    unsigned r;
    asm volatile("v_cvt_pk_bf16_f32 %0, %1, %2" : "=v"(r) : "v"(lo), "v"(hi));
    return r;
}

__global__ __launch_bounds__(NT) void ncc_main(
    const float* __restrict__ Jg,  // y_pred
    const float* __restrict__ Ig,  // y_true
    double* __restrict__ acc)
{
    __shared__ float  sA[SROW * SPITCH];   // I staged (zero-masked)
    __shared__ float  sB[SROW * SPITCH];   // J staged
    __shared__ float  tb[4][16 * TPITCH];  // per-wave V-transpose buffer
    __shared__ double sred[4];

    const int xb = blockIdx.x * 64;   // block output cols [xb, xb+64)
    const int yb = blockIdx.y * 16;   // block output rows [yb, yb+16)
    const int bb = blockIdx.z;
    const int t  = threadIdx.x;

    const float* __restrict__ Ib = Ig + (size_t)bb * (H * W);
    const float* __restrict__ Jb = Jg + (size_t)bb * (H * W);

    // ---- stage 24 x 80 (I and J), zero outside the image ----
    #pragma unroll
    for (int k = 0; k < 8; ++k) {
        const int idx = t + k * NT;
        if (idx < SROW * SCOL) {
            const int row = idx / SCOL;
            const int col = idx - row * SCOL;
            const int rg = yb - 4 + row;
            const int cg = xb - 4 + col;
            const float m = ((unsigned)rg < (unsigned)H && (unsigned)cg < (unsigned)W) ? 1.0f : 0.0f;
            const int rc = min(max(rg, 0), H - 1);
            const int cc = min(max(cg, 0), W - 1);
            sA[row * SPITCH + col] = Ib[(size_t)rc * W + cc] * m;
            sB[row * SPITCH + col] = Jb[(size_t)rc * W + cc] * m;
        }
    }
    __syncthreads();

    const int w    = t >> 6;        // wave id: output cols [xb+16w, xb+16w+16)
    const int lane = t & 63;
    const int m16  = lane & 15;
    const int g    = lane >> 4;

    // banded-ones constant, identical for pass-V A and pass-H B:
    // elem i holds k = 8g+i ; value 1 iff m16 <= k <= m16+8
    bf16x8 band;
    #pragma unroll
    for (int i = 0; i < 8; ++i) {
        const int k = 8 * g + i;
        band[i] = (short)((k >= m16 && k <= m16 + 8) ? 0x3F80 : 0);
    }
    const f32x4 zacc = {0.f, 0.f, 0.f, 0.f};

    // ---- pass V: vertical 9-row sums, 5 quantities x 2 col-tiles ----
    // B[k][n]: lane n=m16, k=8g+i -> staged col 16w+16T+m16, staged row k
    f32x4 vacc[5][2];
    #pragma unroll
    for (int T = 0; T < 2; ++T) {
        float fi[8], fj[8];
        const int cidx = (w << 4) + (T << 4) + m16;
        #pragma unroll
        for (int i = 0; i < 8; ++i) {
            const int k = 8 * g + i;
            float vi = 0.f, vj = 0.f;
            if (k < SROW) {  // g==3 rows don't exist; band is 0 there anyway
                vi = sA[k * SPITCH + cidx];
                vj = sB[k * SPITCH + cidx];
            }
            fi[i] = vi; fj[i] = vj;
        }
        bfr q0, q1, q2, q3, q4;
        #pragma unroll
        for (int p = 0; p < 4; ++p) {
            const float a0 = fi[2*p], a1 = fi[2*p+1];
            const float b0 = fj[2*p], b1 = fj[2*p+1];
            q0.u[p] = cvt2(a0, a1);
            q1.u[p] = cvt2(b0, b1);
            q2.u[p] = cvt2(a0 * a0, a1 * a1);
            q3.u[p] = cvt2(b0 * b0, b1 * b1);
            q4.u[p] = cvt2(a0 * b0, a1 * b1);
        }
        vacc[0][T] = __builtin_amdgcn_mfma_f32_16x16x32_bf16(band, q0.v, zacc, 0, 0, 0);
        vacc[1][T] = __builtin_amdgcn_mfma_f32_16x16x32_bf16(band, q1.v, zacc, 0, 0, 0);
        vacc[2][T] = __builtin_amdgcn_mfma_f32_16x16x32_bf16(band, q2.v, zacc, 0, 0, 0);
        vacc[3][T] = __builtin_amdgcn_mfma_f32_16x16x32_bf16(band, q3.v, zacc, 0, 0, 0);
        vacc[4][T] = __builtin_amdgcn_mfma_f32_16x16x32_bf16(band, q4.v, zacc, 0, 0, 0);
    }

    // ---- pass H: transpose V per quantity (wave-private LDS, in-order DS),
    //      then horizontal 9-col sums via band as B-operand ----
    float* tw = tb[w];
    f32x4 hacc[5];
    #pragma unroll
    for (int q = 0; q < 5; ++q) {
        // V C/D layout: lane holds rows 4g+r, col 16T+m16
        #pragma unroll
        for (int T = 0; T < 2; ++T)
            #pragma unroll
            for (int r = 0; r < 4; ++r)
                tw[(4 * g + r) * TPITCH + (T << 4) + m16] = vacc[q][T][r];
        asm volatile("" ::: "memory");
        // A[m][k]: lane m=m16 (out row), k=8g+i (col slot) -> row m16, cols 8g..8g+7
        const float4 lo4 = *(const float4*)&tw[m16 * TPITCH + 8 * g];
        const float4 hi4 = *(const float4*)&tw[m16 * TPITCH + 8 * g + 4];
        asm volatile("" ::: "memory");
        bfr af;
        af.u[0] = cvt2(lo4.x, lo4.y);
        af.u[1] = cvt2(lo4.z, lo4.w);
        af.u[2] = cvt2(hi4.x, hi4.y);
        af.u[3] = cvt2(hi4.z, hi4.w);
        hacc[q] = __builtin_amdgcn_mfma_f32_16x16x32_bf16(af.v, band, zacc, 0, 0, 0);
    }

    // ---- cc for this lane's 4 pixels: row yb+4g+r, col xb+16w+m16 ----
    const float inv = 1.0f / 81.0f;
    float accv = 0.f;
    #pragma unroll
    for (int r = 0; r < 4; ++r) {
        const float uI    = hacc[0][r] * inv;
        const float uJ    = hacc[1][r] * inv;
        const float cross = hacc[4][r] * inv - uI * uJ;
        const float Iv    = hacc[2][r] * inv - uI * uI;
        const float Jv    = hacc[3][r] * inv - uJ * uJ;
        accv += cross * rsqrtf(fmaxf(Iv * Jv, 1e-7f));
    }

    // ---- reduce: wave -> LDS -> one atomic per block ----
    #pragma unroll
    for (int off = 32; off > 0; off >>= 1)
        accv += __shfl_down(accv, off);
    if (lane == 0)
        sred[w] = (double)accv;
    __syncthreads();
    if (t == 0) {
        double s = sred[0] + sred[1] + sred[2] + sred[3];
        atomicAdd(acc, s);
    }
}

extern "C" void kernel_launch(void* const* d_in, const int* in_sizes, int n_in,
                              void* d_out, int out_size, void* d_ws, size_t ws_size,
                              hipStream_t stream) {
    const float* y_pred = (const float*)d_in[0];  // Ji
    const float* y_true = (const float*)d_in[1];  // Ii
    float* out = (float*)d_out;
    double* accp = (double*)d_ws;

    ncc_zero<<<dim3(1), dim3(1), 0, stream>>>(accp);
    // 16 x 64 x 8 = 8192 blocks; each block = 16 rows x 64 cols of one image
    dim3 grid(W / 64, H / 16, NB);
    ncc_main<<<grid, dim3(NT), 0, stream>>>(y_pred, y_true, accp);
    ncc_finalize<<<dim3(1), dim3(1), 0, stream>>>(accp, out);
}

// Round 12
// 41.534 us; speedup vs baseline: 2.8307x; 2.8307x over previous
//
#include <hip/hip_runtime.h>

#define H 1024
#define W 1024
#define NB 8
#define TY 8
#define NT 256
#define WCOLS 256           /* output cols per wave */
#define LW (WCOLS + 8)      /* 264: 4-col halo each side */

__global__ void ncc_zero(double* acc) { *acc = 0.0; }

__global__ void ncc_finalize(const double* __restrict__ acc, float* __restrict__ out) {
    out[0] = 1.0f - (float)(*acc * (1.0 / 8388608.0));  // 8*1024*1024 pixels
}

__global__ __launch_bounds__(NT) void ncc_main(
    const float* __restrict__ Jg,  // y_pred
    const float* __restrict__ Ig,  // y_true
    double* __restrict__ acc)
{
    __shared__ float vs[NT / 64][5][LW];   // wave-private vertical sums: I,J,II,JJ,IJ
    __shared__ double sred[NT / 64];

    const int b    = blockIdx.x;
    const int y0   = blockIdx.y * TY;
    const int t    = threadIdx.x;
    const int w    = t >> 6;
    const int lane = t & 63;
    const int xw   = lane << 2;            // within-wave col base (0..252)
    const int x0   = (w << 8) + xw;        // global col

    const float* __restrict__ Ib = Ig + (size_t)b * (H * W);
    const float* __restrict__ Jb = Jg + (size_t)b * (H * W);

    // halo: lanes 0..3 left halo cols, lanes 4..7 right halo cols (one scalar col each)
    const int   wbase = w << 8;
    const bool  isH   = (lane < 8);
    const int   hc    = (lane < 4) ? (wbase - 4 + lane) : (wbase + WCOLS + (lane - 4));
    const float mh    = (isH && (unsigned)hc < (unsigned)W) ? 1.0f : 0.0f;
    const int   hcc   = min(max(hc, 0), W - 1);
    const int   hslot = (lane < 4) ? lane : (WCOLS + lane);  // 0..3 / 260..263

    float sI[4]={0,0,0,0}, sJ[4]={0,0,0,0}, sII[4]={0,0,0,0}, sJJ[4]={0,0,0,0}, sIJ[4]={0,0,0,0};
    float hs0=0, hs1=0, hs2=0, hs3=0, hs4=0;

    // ---- pipelined init: rows y0-4 .. y0+4, one row ahead in flight ----
    float4 civ, cjv; float chi = 0, chj = 0, cm;
    {
        const int r  = y0 - 4;
        cm = ((unsigned)r < (unsigned)H) ? 1.0f : 0.0f;
        const int rc = min(max(r, 0), H - 1);
        civ = *(const float4*)(Ib + (size_t)rc * W + x0);
        cjv = *(const float4*)(Jb + (size_t)rc * W + x0);
        if (isH) { chi = Ib[(size_t)rc * W + hcc]; chj = Jb[(size_t)rc * W + hcc]; }
    }
    #pragma unroll 1
    for (int k = -4; k <= 4; ++k) {
        const int   rn  = y0 + ((k < 4) ? (k + 1) : 4);
        const float nm  = ((unsigned)(y0 + k + 1) < (unsigned)H) ? 1.0f : 0.0f;
        const int   rnc = min(max(rn, 0), H - 1);
        float4 niv = *(const float4*)(Ib + (size_t)rnc * W + x0);
        float4 njv = *(const float4*)(Jb + (size_t)rnc * W + x0);
        float  nhi = 0, nhj = 0;
        if (isH) { nhi = Ib[(size_t)rnc * W + hcc]; nhj = Jb[(size_t)rnc * W + hcc]; }
        {
            const float fi[4] = {civ.x * cm, civ.y * cm, civ.z * cm, civ.w * cm};
            const float fj[4] = {cjv.x * cm, cjv.y * cm, cjv.z * cm, cjv.w * cm};
            #pragma unroll
            for (int c = 0; c < 4; ++c) {
                sI[c] += fi[c]; sJ[c] += fj[c];
                sII[c] += fi[c] * fi[c]; sJJ[c] += fj[c] * fj[c]; sIJ[c] += fi[c] * fj[c];
            }
            const float mm = cm * mh;
            const float hi = chi * mm, hj = chj * mm;
            hs0 += hi; hs1 += hj; hs2 += hi * hi; hs3 += hj * hj; hs4 += hi * hj;
        }
        civ = niv; cjv = njv; chi = nhi; chj = nhj; cm = nm;
    }

    // two prefetch sets (A/B): distance-2 software pipeline for the slide rows
    float4 piaA, pjaA, pisA, pjsA; float phiaA=0, phjaA=0, phisA=0, phjsA=0, pmaA, pmsA;
    float4 piaB, pjaB, pisB, pjsB; float phiaB=0, phjaB=0, phisB=0, phjsB=0, pmaB, pmsB;

#define LOADSET(S, yy) do {                                                             \
        const int ra_ = (yy) + 5, rs_ = (yy) - 4;                                       \
        pma##S = (ra_ < H) ? 1.0f : 0.0f;                                               \
        pms##S = (rs_ >= 0) ? 1.0f : 0.0f;                                              \
        const int rca_ = min(ra_, H - 1), rcs_ = max(rs_, 0);                           \
        pia##S = *(const float4*)(Ib + (size_t)rca_ * W + x0);                          \
        pja##S = *(const float4*)(Jb + (size_t)rca_ * W + x0);                          \
        pis##S = *(const float4*)(Ib + (size_t)rcs_ * W + x0);                          \
        pjs##S = *(const float4*)(Jb + (size_t)rcs_ * W + x0);                          \
        if (isH) {                                                                      \
            phia##S = Ib[(size_t)rca_ * W + hcc]; phja##S = Jb[(size_t)rca_ * W + hcc]; \
            phis##S = Ib[(size_t)rcs_ * W + hcc]; phjs##S = Jb[(size_t)rcs_ * W + hcc]; \
        }                                                                               \
    } while (0)

    LOADSET(A, y0);        // rows for slide(y0)
    LOADSET(B, y0 + 1);    // rows for slide(y0+1)

    const float inv = 1.0f / 81.0f;
    float accv = 0.0f;

#define ITER(yy, S) do {                                                                   \
        *(float4*)&vs[w][0][4 + xw] = make_float4(sI[0],  sI[1],  sI[2],  sI[3]);          \
        *(float4*)&vs[w][1][4 + xw] = make_float4(sJ[0],  sJ[1],  sJ[2],  sJ[3]);          \
        *(float4*)&vs[w][2][4 + xw] = make_float4(sII[0], sII[1], sII[2], sII[3]);         \
        *(float4*)&vs[w][3][4 + xw] = make_float4(sJJ[0], sJJ[1], sJJ[2], sJJ[3]);         \
        *(float4*)&vs[w][4][4 + xw] = make_float4(sIJ[0], sIJ[1], sIJ[2], sIJ[3]);         \
        if (isH) {                                                                         \
            vs[w][0][hslot] = hs0; vs[w][1][hslot] = hs1; vs[w][2][hslot] = hs2;           \
            vs[w][3][hslot] = hs3; vs[w][4][hslot] = hs4;                                  \
        }                                                                                  \
        asm volatile("" ::: "memory");                                                     \
        float4 a0 = *(const float4*)&vs[w][0][xw], c0 = *(const float4*)&vs[w][0][xw + 8]; \
        float4 a1 = *(const float4*)&vs[w][1][xw], c1 = *(const float4*)&vs[w][1][xw + 8]; \
        float4 a2 = *(const float4*)&vs[w][2][xw], c2 = *(const float4*)&vs[w][2][xw + 8]; \
        float4 a3 = *(const float4*)&vs[w][3][xw], c3 = *(const float4*)&vs[w][3][xw + 8]; \
        float4 a4 = *(const float4*)&vs[w][4][xw], c4 = *(const float4*)&vs[w][4][xw + 8]; \
        asm volatile("" ::: "memory");                                                     \
        const float T0 = sI[0]  + sI[1]  + sI[2]  + sI[3];                                 \
        const float T1 = sJ[0]  + sJ[1]  + sJ[2]  + sJ[3];                                 \
        const float T2 = sII[0] + sII[1] + sII[2] + sII[3];                                \
        const float T3 = sJJ[0] + sJJ[1] + sJJ[2] + sJJ[3];                                \
        const float T4 = sIJ[0] + sIJ[1] + sIJ[2] + sIJ[3];                                \
        {                                                                                  \
            const float fa0 = pia##S.x * pma##S, fa1 = pia##S.y * pma##S;                  \
            const float fa2 = pia##S.z * pma##S, fa3 = pia##S.w * pma##S;                  \
            const float ga0 = pja##S.x * pma##S, ga1 = pja##S.y * pma##S;                  \
            const float ga2 = pja##S.z * pma##S, ga3 = pja##S.w * pma##S;                  \
            const float fs0 = pis##S.x * pms##S, fs1 = pis##S.y * pms##S;                  \
            const float fs2 = pis##S.z * pms##S, fs3 = pis##S.w * pms##S;                  \
            const float gs0 = pjs##S.x * pms##S, gs1 = pjs##S.y * pms##S;                  \
            const float gs2 = pjs##S.z * pms##S, gs3 = pjs##S.w * pms##S;                  \
            sI[0] += fa0 - fs0; sI[1] += fa1 - fs1; sI[2] += fa2 - fs2; sI[3] += fa3 - fs3;\
            sJ[0] += ga0 - gs0; sJ[1] += ga1 - gs1; sJ[2] += ga2 - gs2; sJ[3] += ga3 - gs3;\
            sII[0] += fa0*fa0 - fs0*fs0; sII[1] += fa1*fa1 - fs1*fs1;                      \
            sII[2] += fa2*fa2 - fs2*fs2; sII[3] += fa3*fa3 - fs3*fs3;                      \
            sJJ[0] += ga0*ga0 - gs0*gs0; sJJ[1] += ga1*ga1 - gs1*gs1;                      \
            sJJ[2] += ga2*ga2 - gs2*gs2; sJJ[3] += ga3*ga3 - gs3*gs3;                      \
            sIJ[0] += fa0*ga0 - fs0*gs0; sIJ[1] += fa1*ga1 - fs1*gs1;                      \
            sIJ[2] += fa2*ga2 - fs2*gs2; sIJ[3] += fa3*ga3 - fs3*gs3;                      \
            const float hia = phia##S * (pma##S * mh), hja = phja##S * (pma##S * mh);      \
            const float his = phis##S * (pms##S * mh), hjs = phjs##S * (pms##S * mh);      \
            hs0 += hia - his;                                                              \
            hs1 += hja - hjs;                                                              \
            hs2 += hia * hia - his * his;                                                  \
            hs3 += hja * hja - hjs * hjs;                                                  \
            hs4 += hia * hja - his * hjs;                                                  \
        }                                                                                  \
        LOADSET(S, (yy) + 2);                                                              \
        float h0[4], h1[4], h2[4], h3[4], h4[4];                                           \
        HTAP(a0, c0, T0, h0); HTAP(a1, c1, T1, h1); HTAP(a2, c2, T2, h2);                  \
        HTAP(a3, c3, T3, h3); HTAP(a4, c4, T4, h4);                                        \
        _Pragma("unroll")                                                                  \
        for (int c = 0; c < 4; ++c) {                                                      \
            const float uI    = h0[c] * inv;                                               \
            const float uJ    = h1[c] * inv;                                               \
            const float cross = h4[c] * inv - uI * uJ;                                     \
            const float Iv    = h2[c] * inv - uI * uI;                                     \
            const float Jv    = h3[c] * inv - uJ * uJ;                                     \
            accv += cross * rsqrtf(fmaxf(Iv * Jv, 1e-7f));                                 \
        }                                                                                  \
    } while (0)

#define HTAP(a, cg, T, o) do {                                                             \
        float s_ = a.x + a.y + a.z + a.w + cg.x + T;                                       \
        o[0] = s_; s_ += cg.y - a.x;                                                       \
        o[1] = s_; s_ += cg.z - a.y;                                                       \
        o[2] = s_; s_ += cg.w - a.z;                                                       \
        o[3] = s_;                                                                         \
    } while (0)

    #pragma unroll 1
    for (int i = 0; i < TY; i += 2) {
        ITER(y0 + i,     A);
        ITER(y0 + i + 1, B);
    }

#undef ITER
#undef LOADSET
#undef HTAP

    // wave reduce (64 lanes) -> LDS -> one atomic per block (cold path)
    #pragma unroll
    for (int off = 32; off > 0; off >>= 1)
        accv += __shfl_down(accv, off);
    if (lane == 0)
        sred[w] = (double)accv;
    __syncthreads();
    if (t == 0) {
        double s = sred[0];
        #pragma unroll
        for (int q = 1; q < NT / 64; ++q) s += sred[q];
        atomicAdd(acc, s);
    }
}

extern "C" void kernel_launch(void* const* d_in, const int* in_sizes, int n_in,
                              void* d_out, int out_size, void* d_ws, size_t ws_size,
                              hipStream_t stream) {
    const float* y_pred = (const float*)d_in[0];  // Ji
    const float* y_true = (const float*)d_in[1];  // Ii
    float* out = (float*)d_out;
    double* accp = (double*)d_ws;

    ncc_zero<<<dim3(1), dim3(1), 0, stream>>>(accp);
    dim3 grid(NB, H / TY);  // 8 x 128 = 1024 blocks; distance-2 prefetch pipeline
    ncc_main<<<grid, dim3(NT), 0, stream>>>(y_pred, y_true, accp);
    ncc_finalize<<<dim3(1), dim3(1), 0, stream>>>(accp, out);
}